// Round 3
// baseline (2426.369 us; speedup 1.0000x reference)
//
#include <hip/hip_runtime.h>
#include <float.h>

#define NEMB 1024
#define EDIM 256
#define BM   64
#define HW   4096   // 64*64
#define NB   8
#define ZQ_ELEMS 33554432   // 32*256*4096

// Replicates numpy FLOAT_pairwise_sum of squares for n=256 contiguous values:
// two 128-blocks (recursion n2=128), each with 8 scalar accumulators
// r[j] += a[8i+j], tree-combined ((r0+r1)+(r2+r3))+((r4+r5)+(r6+r7)),
// then blk0 + blk1. Each square rounded separately (contract off).
template <typename F>
__device__ __forceinline__ float np_sumsq_256(F get) {
#pragma clang fp contract(off)
    float blk[2];
#pragma unroll
    for (int h = 0; h < 2; ++h) {
        const int base = h * 128;
        float r[8];
#pragma unroll
        for (int j = 0; j < 8; ++j) {
            float v = get(base + j);
            r[j] = v * v;                      // rounded square
        }
        for (int i = 8; i < 128; i += 8) {
#pragma unroll
            for (int j = 0; j < 8; ++j) {
                float v = get(base + i + j);
                float p = v * v;               // rounded square (no fma fusion)
                r[j] = r[j] + p;
            }
        }
        blk[h] = ((r[0] + r[1]) + (r[2] + r[3])) + ((r[4] + r[5]) + (r[6] + r[7]));
    }
    return blk[0] + blk[1];
}

// e_sq[n] = numpy-pairwise sum of emb[n][k]^2, one thread per codebook row.
__global__ __launch_bounds__(256) void esq_kernel(const float* __restrict__ emb,
                                                  float* __restrict__ esq) {
    int n = blockIdx.x * 256 + threadIdx.x;
    const float* e = emb + (size_t)n * EDIM;
    esq[n] = np_sumsq_256([&](int k) { return e[k]; });
}

__global__ __launch_bounds__(256) void vq_kernel(const float* __restrict__ z,
                                                 const float* __restrict__ emb,
                                                 const float* __restrict__ esq,
                                                 float* __restrict__ out) {
    // z tile in LDS, k-major: zl[k*BM + r]. 64 KiB.
    __shared__ float zl[BM * EDIM];

    const int t   = threadIdx.x;
    const int blk = blockIdx.x;           // 2048 blocks: 64 per batch image
    const int b   = blk >> 6;
    const int hw0 = (blk & 63) * BM;
    const float* zb = z + (size_t)b * EDIM * HW;

    // ---- stage z tile: 4096 float4, 16 per thread, coalesced along hw ----
#pragma unroll
    for (int pass = 0; pass < 16; ++pass) {
        int f4 = pass * 256 + t;
        int r4 = (f4 & 15) * 4;
        int k  = f4 >> 4;
        float4 v = *(const float4*)(zb + (size_t)k * HW + hw0 + r4);
        *(float4*)(&zl[k * BM + r4]) = v;
    }
    __syncthreads();

    const int r = t & 63;                 // my row (lane id)
    // z_sq with exact numpy pairwise semantics
    const float zsq = np_sumsq_256([&](int k) { return zl[k * BM + r]; });

    // wave id -> codebook quarter (uniform -> scalar emb loads)
    const int q = __builtin_amdgcn_readfirstlane(t >> 6);

    float best = FLT_MAX;
    int   bidx = 0;
    for (int n0 = q * 256; n0 < q * 256 + 256; n0 += NB) {
        float acc[NB];
#pragma unroll
        for (int j = 0; j < NB; ++j) acc[j] = 0.f;

        // e_z: strictly sequential fp32 FMA over k=0..255, single chain per
        // codeword (BLAS sgemm microkernel accumulation order).
        for (int k = 0; k < EDIM; k += 8) {
            float zk[8];
#pragma unroll
            for (int u = 0; u < 8; ++u) zk[u] = zl[(k + u) * BM + r];
#pragma unroll
            for (int j = 0; j < NB; ++j) {
                const float* er = emb + (size_t)(n0 + j) * EDIM + k;
                float a = acc[j];
#pragma unroll
                for (int u = 0; u < 8; ++u) a = fmaf(zk[u], er[u], a);
                acc[j] = a;
            }
        }
#pragma unroll
        for (int j = 0; j < NB; ++j) {
            // numpy: dist = RN( RN(zsq + esq) - 2*ez );  2*ez exact, so the
            // fused form is bit-identical to numpy's two-step rounding.
            float t1 = zsq + esq[n0 + j];
            float d  = fmaf(-2.f, acc[j], t1);
            if (d < best) { best = d; bidx = n0 + j; }   // strict <: first-index
        }
    }

    // ---- cross-wave (min,idx) reduction, reusing zl ----
    __syncthreads();                        // all zl reads done
    float* rv   = zl;                       // [256] best value
    int*   ri   = (int*)(zl + 256);         // [256] best idx
    int*   ifin = (int*)(zl + 512);         // [64]  final idx per row
    rv[t] = best;
    ri[t] = bidx;
    __syncthreads();
    if (t < 64) {
        float bv = rv[t];
        int   bi = ri[t];
#pragma unroll
        for (int w = 1; w < 4; ++w) {
            float v = rv[t + 64 * w];
            int   i = ri[t + 64 * w];
            // waves cover ascending idx ranges; strict < keeps lowest idx on ties
            if (v < bv) { bv = v; bi = i; }
        }
        ifin[t] = bi;
        out[(size_t)ZQ_ELEMS + (size_t)blk * BM + t] = (float)bi;  // idx as float
    }
    __syncthreads();

    // ---- z_q[b][c][hw] = emb[idx[hw]][c], coalesced float4 along hw ----
    float* zq = out + (size_t)b * EDIM * HW;
#pragma unroll
    for (int pass = 0; pass < 16; ++pass) {
        int f4 = pass * 256 + t;
        int r4 = (f4 & 15) * 4;
        int c  = f4 >> 4;
        float4 v;
        v.x = emb[(size_t)ifin[r4 + 0] * EDIM + c];
        v.y = emb[(size_t)ifin[r4 + 1] * EDIM + c];
        v.z = emb[(size_t)ifin[r4 + 2] * EDIM + c];
        v.w = emb[(size_t)ifin[r4 + 3] * EDIM + c];
        *(float4*)(zq + (size_t)c * HW + hw0 + r4) = v;
    }
}

extern "C" void kernel_launch(void* const* d_in, const int* in_sizes, int n_in,
                              void* d_out, int out_size, void* d_ws, size_t ws_size,
                              hipStream_t stream) {
    const float* z   = (const float*)d_in[0];   // [32,256,64,64]
    const float* emb = (const float*)d_in[1];   // [1024,256]
    float* out = (float*)d_out;                 // 33554432 z_q + 131072 idx (as float)
    float* esq = (float*)d_ws;                  // 1024 floats scratch

    esq_kernel<<<NEMB / 256, 256, 0, stream>>>(emb, esq);
    vq_kernel<<<131072 / BM, 256, 0, stream>>>(z, emb, esq, out);
}

// Round 4
// 1459.795 us; speedup vs baseline: 1.6621x; 1.6621x over previous
//
#include <hip/hip_runtime.h>
#include <float.h>

#define NEMB 1024
#define EDIM 256
#define BM   64
#define HW   4096   // 64*64
#define NB   8
#define NT   512    // threads/block: 8 waves sharing one 64 KiB z tile
#define ZQ_ELEMS 33554432   // 32*256*4096

// Replicates numpy FLOAT_pairwise_sum of squares for n=256 contiguous values:
// two 128-blocks (recursion n2=128), each with 8 scalar accumulators
// r[j] += a[8i+j], tree-combined ((r0+r1)+(r2+r3))+((r4+r5)+(r6+r7)),
// then blk0 + blk1. Each square rounded separately (contract off).
template <typename F>
__device__ __forceinline__ float np_sumsq_256(F get) {
#pragma clang fp contract(off)
    float blk[2];
#pragma unroll
    for (int h = 0; h < 2; ++h) {
        const int base = h * 128;
        float r[8];
#pragma unroll
        for (int j = 0; j < 8; ++j) {
            float v = get(base + j);
            r[j] = v * v;
        }
        for (int i = 8; i < 128; i += 8) {
#pragma unroll
            for (int j = 0; j < 8; ++j) {
                float v = get(base + i + j);
                float p = v * v;
                r[j] = r[j] + p;
            }
        }
        blk[h] = ((r[0] + r[1]) + (r[2] + r[3])) + ((r[4] + r[5]) + (r[6] + r[7]));
    }
    return blk[0] + blk[1];
}

__global__ __launch_bounds__(256) void esq_kernel(const float* __restrict__ emb,
                                                  float* __restrict__ esq) {
    int n = blockIdx.x * 256 + threadIdx.x;
    const float* e = emb + (size_t)n * EDIM;
    esq[n] = np_sumsq_256([&](int k) { return e[k]; });
}

__global__ __launch_bounds__(NT, 4) void vq_kernel(const float* __restrict__ z,
                                                   const float* __restrict__ emb,
                                                   const float* __restrict__ esq,
                                                   float* __restrict__ out) {
    // z tile, k-major: zl[k*BM + r]. 64 KiB shared by 8 waves -> 2 blocks/CU,
    // 16 waves/CU (50% occupancy). Reused for the reduction after the loop.
    __shared__ float zl[BM * EDIM];

    const int t   = threadIdx.x;
    const int blk = blockIdx.x;           // 2048 blocks: 64 per batch image
    const int b   = blk >> 6;
    const int hw0 = (blk & 63) * BM;
    const float* zb = z + (size_t)b * EDIM * HW;

    // ---- stage z tile: 4096 float4, 8 per thread, coalesced along hw ----
#pragma unroll
    for (int pass = 0; pass < 8; ++pass) {
        int f4 = pass * NT + t;
        int r4 = (f4 & 15) * 4;
        int k  = f4 >> 4;
        float4 v = *(const float4*)(zb + (size_t)k * HW + hw0 + r4);
        *(float4*)(&zl[k * BM + r4]) = v;
    }
    __syncthreads();

    const int r = t & 63;                 // my row (lane id)
    // z_sq with exact numpy pairwise semantics (redundant per wave; cheap)
    const float zsq = np_sumsq_256([&](int k) { return zl[k * BM + r]; });

    // wave id -> 128-codeword range (uniform -> scalar emb loads)
    const int q = __builtin_amdgcn_readfirstlane(t >> 6);

    float best = FLT_MAX;
    int   bidx = 0;
    for (int n0 = q * 128; n0 < q * 128 + 128; n0 += NB) {
        float acc[NB];
#pragma unroll
        for (int j = 0; j < NB; ++j) acc[j] = 0.f;

        // e_z: strictly sequential fp32 FMA over k=0..255 per codeword
        // (numpy/BLAS microkernel order). k-loop unrolled x2 with two z
        // register buffers so next chunk's ds_reads overlap current FMAs.
        float zk[8], zk2[8];
#pragma unroll
        for (int u = 0; u < 8; ++u) zk[u] = zl[u * BM + r];
        for (int k = 0; k < EDIM; k += 16) {
#pragma unroll
            for (int u = 0; u < 8; ++u) zk2[u] = zl[(k + 8 + u) * BM + r];
#pragma unroll
            for (int j = 0; j < NB; ++j) {
                const float* er = emb + (size_t)(n0 + j) * EDIM + k;
                float a = acc[j];
#pragma unroll
                for (int u = 0; u < 8; ++u) a = fmaf(zk[u], er[u], a);
                acc[j] = a;
            }
            if (k + 16 < EDIM) {
#pragma unroll
                for (int u = 0; u < 8; ++u) zk[u] = zl[(k + 16 + u) * BM + r];
            }
#pragma unroll
            for (int j = 0; j < NB; ++j) {
                const float* er = emb + (size_t)(n0 + j) * EDIM + k + 8;
                float a = acc[j];
#pragma unroll
                for (int u = 0; u < 8; ++u) a = fmaf(zk2[u], er[u], a);
                acc[j] = a;
            }
        }
#pragma unroll
        for (int j = 0; j < NB; ++j) {
            // numpy: dist = RN( RN(zsq+esq) - 2*ez ); 2*ez exact -> fma form
            // is bit-identical.
            float t1 = zsq + esq[n0 + j];
            float d  = fmaf(-2.f, acc[j], t1);
            if (d < best) { best = d; bidx = n0 + j; }   // strict <: first-index
        }
    }

    // ---- cross-wave (min,idx) reduction, reusing zl ----
    __syncthreads();                        // all zl reads done
    float* rv   = zl;                       // [512] best value
    int*   ri   = (int*)(zl + NT);          // [512] best idx
    int*   ifin = (int*)(zl + 2 * NT);      // [64]  final idx per row
    rv[t] = best;
    ri[t] = bidx;
    __syncthreads();
    if (t < 64) {
        float bv = rv[t];
        int   bi = ri[t];
#pragma unroll
        for (int w = 1; w < 8; ++w) {
            float v = rv[t + 64 * w];
            int   i = ri[t + 64 * w];
            // waves cover ascending idx ranges; strict < keeps lowest idx
            if (v < bv) { bv = v; bi = i; }
        }
        ifin[t] = bi;
        out[(size_t)ZQ_ELEMS + (size_t)blk * BM + t] = (float)bi;  // idx as float
    }
    __syncthreads();

    // ---- z_q[b][c][hw] = emb[idx[hw]][c], coalesced float4 along hw ----
    float* zq = out + (size_t)b * EDIM * HW;
#pragma unroll
    for (int pass = 0; pass < 8; ++pass) {
        int f4 = pass * NT + t;
        int r4 = (f4 & 15) * 4;
        int c  = f4 >> 4;
        float4 v;
        v.x = emb[(size_t)ifin[r4 + 0] * EDIM + c];
        v.y = emb[(size_t)ifin[r4 + 1] * EDIM + c];
        v.z = emb[(size_t)ifin[r4 + 2] * EDIM + c];
        v.w = emb[(size_t)ifin[r4 + 3] * EDIM + c];
        *(float4*)(zq + (size_t)c * HW + hw0 + r4) = v;
    }
}

extern "C" void kernel_launch(void* const* d_in, const int* in_sizes, int n_in,
                              void* d_out, int out_size, void* d_ws, size_t ws_size,
                              hipStream_t stream) {
    const float* z   = (const float*)d_in[0];   // [32,256,64,64]
    const float* emb = (const float*)d_in[1];   // [1024,256]
    float* out = (float*)d_out;                 // 33554432 z_q + 131072 idx (as float)
    float* esq = (float*)d_ws;                  // 1024 floats scratch

    esq_kernel<<<NEMB / 256, 256, 0, stream>>>(emb, esq);
    vq_kernel<<<131072 / BM, NT, 0, stream>>>(z, emb, esq, out);
}

// Round 5
// 1363.637 us; speedup vs baseline: 1.7793x; 1.0705x over previous
//
#include <hip/hip_runtime.h>
#include <float.h>

#define NEMB 1024
#define EDIM 256
#define BM   64
#define HW   4096   // 64*64
#define NB   8
#define NT   1024   // threads/block: 16 waves share one 64 KiB z tile
#define NW   (NT / 64)
#define ZQ_ELEMS 33554432   // 32*256*4096

// numpy FLOAT_pairwise_sum of squares, n=256: two 128-blocks, 8 accumulators
// r[j] += a[8i+j], tree-combine ((r0+r1)+(r2+r3))+((r4+r5)+(r6+r7)), then
// blk0+blk1. Squares rounded separately (contract off).
template <typename F>
__device__ __forceinline__ float np_sumsq_256(F get) {
#pragma clang fp contract(off)
    float blk[2];
#pragma unroll
    for (int h = 0; h < 2; ++h) {
        const int base = h * 128;
        float r[8];
#pragma unroll
        for (int j = 0; j < 8; ++j) {
            float v = get(base + j);
            r[j] = v * v;
        }
        for (int i = 8; i < 128; i += 8) {
#pragma unroll
            for (int j = 0; j < 8; ++j) {
                float v = get(base + i + j);
                float p = v * v;
                r[j] = r[j] + p;
            }
        }
        blk[h] = ((r[0] + r[1]) + (r[2] + r[3])) + ((r[4] + r[5]) + (r[6] + r[7]));
    }
    return blk[0] + blk[1];
}

__global__ __launch_bounds__(256) void esq_kernel(const float* __restrict__ emb,
                                                  float* __restrict__ esq) {
    int n = blockIdx.x * 256 + threadIdx.x;
    const float* e = emb + (size_t)n * EDIM;
    esq[n] = np_sumsq_256([&](int k) { return e[k]; });
}

__global__ __launch_bounds__(NT, 8) void vq_kernel(const float* __restrict__ z,
                                                   const float* __restrict__ emb,
                                                   const float* __restrict__ esq,
                                                   float* __restrict__ out) {
    // z tile, k-major: zl[k*BM + r]. 64 KiB shared by 16 waves -> 2 blocks/CU,
    // 32 waves/CU (100% occupancy). Reused for the reduction after the loop.
    __shared__ float zl[BM * EDIM];

    const int t   = threadIdx.x;
    const int blk = blockIdx.x;           // 2048 blocks: 64 per batch image
    const int b   = blk >> 6;
    const int hw0 = (blk & 63) * BM;
    const float* zb = z + (size_t)b * EDIM * HW;

    // ---- stage z tile: 4096 float4, 4 per thread, coalesced along hw ----
#pragma unroll
    for (int pass = 0; pass < 4; ++pass) {
        int f4 = pass * NT + t;
        int r4 = (f4 & 15) * 4;
        int k  = f4 >> 4;
        float4 v = *(const float4*)(zb + (size_t)k * HW + hw0 + r4);
        *(float4*)(&zl[k * BM + r4]) = v;
    }
    __syncthreads();

    const int r = t & 63;                 // my row (lane id)
    // z_sq with exact numpy pairwise semantics (redundant per wave; cheap)
    const float zsq = np_sumsq_256([&](int k) { return zl[k * BM + r]; });

    // wave id -> 64-codeword range (uniform -> scalar emb loads)
    const int q = __builtin_amdgcn_readfirstlane(t >> 6);

    float best = FLT_MAX;
    int   bidx = 0;
    for (int n0 = q * 64; n0 < q * 64 + 64; n0 += NB) {
        float acc[NB];
#pragma unroll
        for (int j = 0; j < NB; ++j) acc[j] = 0.f;

        // e_z: strictly sequential fp32 FMA over k=0..255 per codeword
        // (numpy/BLAS microkernel order). k-loop unrolled x2, two z register
        // buffers so next chunk's ds_reads overlap current FMAs.
        float zk[8], zk2[8];
#pragma unroll
        for (int u = 0; u < 8; ++u) zk[u] = zl[u * BM + r];
        for (int k = 0; k < EDIM; k += 16) {
#pragma unroll
            for (int u = 0; u < 8; ++u) zk2[u] = zl[(k + 8 + u) * BM + r];
#pragma unroll
            for (int j = 0; j < NB; ++j) {
                const float* er = emb + (size_t)(n0 + j) * EDIM + k;
                float a = acc[j];
#pragma unroll
                for (int u = 0; u < 8; ++u) a = fmaf(zk[u], er[u], a);
                acc[j] = a;
            }
            if (k + 16 < EDIM) {
#pragma unroll
                for (int u = 0; u < 8; ++u) zk[u] = zl[(k + 16 + u) * BM + r];
            }
#pragma unroll
            for (int j = 0; j < NB; ++j) {
                const float* er = emb + (size_t)(n0 + j) * EDIM + k + 8;
                float a = acc[j];
#pragma unroll
                for (int u = 0; u < 8; ++u) a = fmaf(zk2[u], er[u], a);
                acc[j] = a;
            }
        }
#pragma unroll
        for (int j = 0; j < NB; ++j) {
            // numpy: dist = RN( RN(zsq+esq) - 2*ez ); 2*ez exact -> fma form
            // is bit-identical.
            float t1 = zsq + esq[n0 + j];
            float d  = fmaf(-2.f, acc[j], t1);
            if (d < best) { best = d; bidx = n0 + j; }   // strict <: first-index
        }
    }

    // ---- cross-wave (min,idx) reduction, reusing zl ----
    __syncthreads();                        // all zl reads done
    float* rv   = zl;                       // [1024] best value
    int*   ri   = (int*)(zl + NT);          // [1024] best idx
    int*   ifin = (int*)(zl + 2 * NT);      // [64]   final idx per row
    rv[t] = best;
    ri[t] = bidx;
    __syncthreads();
    if (t < 64) {
        float bv = rv[t];
        int   bi = ri[t];
#pragma unroll
        for (int w = 1; w < NW; ++w) {
            float v = rv[t + 64 * w];
            int   i = ri[t + 64 * w];
            // waves cover ascending idx ranges; strict < keeps lowest idx
            if (v < bv) { bv = v; bi = i; }
        }
        ifin[t] = bi;
        out[(size_t)ZQ_ELEMS + (size_t)blk * BM + t] = (float)bi;  // idx as float
    }
    __syncthreads();

    // ---- z_q[b][c][hw] = emb[idx[hw]][c], coalesced float4 along hw ----
    float* zq = out + (size_t)b * EDIM * HW;
#pragma unroll
    for (int pass = 0; pass < 4; ++pass) {
        int f4 = pass * NT + t;
        int r4 = (f4 & 15) * 4;
        int c  = f4 >> 4;
        float4 v;
        v.x = emb[(size_t)ifin[r4 + 0] * EDIM + c];
        v.y = emb[(size_t)ifin[r4 + 1] * EDIM + c];
        v.z = emb[(size_t)ifin[r4 + 2] * EDIM + c];
        v.w = emb[(size_t)ifin[r4 + 3] * EDIM + c];
        *(float4*)(zq + (size_t)c * HW + hw0 + r4) = v;
    }
}

extern "C" void kernel_launch(void* const* d_in, const int* in_sizes, int n_in,
                              void* d_out, int out_size, void* d_ws, size_t ws_size,
                              hipStream_t stream) {
    const float* z   = (const float*)d_in[0];   // [32,256,64,64]
    const float* emb = (const float*)d_in[1];   // [1024,256]
    float* out = (float*)d_out;                 // 33554432 z_q + 131072 idx (as float)
    float* esq = (float*)d_ws;                  // 1024 floats scratch

    esq_kernel<<<NEMB / 256, 256, 0, stream>>>(emb, esq);
    vq_kernel<<<131072 / BM, NT, 0, stream>>>(z, emb, esq, out);
}